// Round 8
// baseline (266.445 us; speedup 1.0000x reference)
//
#include <hip/hip_runtime.h>
#include <hip/hip_bf16.h>

#define NPTS   2048
#define IDIM   16
#define HDIM   32
#define CUTSN  8
#define EPSV   1e-5f
#define PSCALE 0.07856742013183862f   /* 1/(sqrt(2)*9) */
#define ICH    16                     /* i-rows per block chunk */
#define IPK    48                     /* floats per ipack row (192B aligned) */

typedef __bf16 bf16x8 __attribute__((ext_vector_type(8)));
typedef float  f32x16 __attribute__((ext_vector_type(16)));

__device__ __forceinline__ float leaky(float x) { return x >= 0.f ? x : 0.2f * x; }

/* ------- two-layer MLP (per-row) + GroupNorm partial sums (+ipack/zero) -------
 * 32 blocks x 64 threads (one wave), one row per thread. partials (256 floats):
 * [g*32 + block] = group sums, [128 + g*32 + block] = group sumsq.
 * When ipack != nullptr also emits the pairwise i-side pack:
 *   [0..31] 8 x {Mx,My,Mz,B1_c} with M_c = A1_c @ nuv_i, [32..39] {p*s, n}. */
template <int K>
__global__ __launch_bounds__(64) void net2_kernel(
    const float* __restrict__ xin,
    const float* __restrict__ W1, const float* __restrict__ b1,
    const float* __restrict__ W2, const float* __restrict__ b2,
    float* __restrict__ out, float* __restrict__ partials,
    float* __restrict__ zbuf,
    const float* __restrict__ points, const float* __restrict__ nuv,
    const float* __restrict__ A1, const float* __restrict__ B1,
    float* __restrict__ ipack)
{
    const int t = threadIdx.x;
    const int i = blockIdx.x * 64 + t;
    if (zbuf) {
#pragma unroll
        for (int e = 0; e < 8; ++e)
            *(float4*)&zbuf[i * HDIM + e * 4] = make_float4(0.f, 0.f, 0.f, 0.f);
    }
    if (ipack) {
        float* ip = ipack + i * IPK;
#pragma unroll
        for (int c = 0; c < 8; ++c) {
            float m0 = 0.f, m1 = 0.f, m2 = 0.f;
#pragma unroll
            for (int a = 0; a < 3; ++a) {
                const float wA = A1[c * 3 + a];
                m0 = fmaf(wA, nuv[i * 9 + a * 3 + 0], m0);
                m1 = fmaf(wA, nuv[i * 9 + a * 3 + 1], m1);
                m2 = fmaf(wA, nuv[i * 9 + a * 3 + 2], m2);
            }
            *(float4*)&ip[c * 4] = make_float4(m0, m1, m2, B1[c]);
        }
        *(float4*)&ip[32] = make_float4(points[i * 3 + 0] * PSCALE,
                                        points[i * 3 + 1] * PSCALE,
                                        points[i * 3 + 2] * PSCALE,
                                        nuv[i * 9 + 0]);
        *(float4*)&ip[36] = make_float4(nuv[i * 9 + 1], nuv[i * 9 + 2], 0.f, 0.f);
        *(float4*)&ip[40] = make_float4(0.f, 0.f, 0.f, 0.f);
        *(float4*)&ip[44] = make_float4(0.f, 0.f, 0.f, 0.f);
    }

    float x[K];
#pragma unroll
    for (int k = 0; k < K; ++k) x[k] = xin[i * K + k];

    float y[HDIM];
#pragma unroll
    for (int h = 0; h < HDIM; ++h) {
        float v = b1[h];
#pragma unroll
        for (int k = 0; k < K; ++k) v = fmaf(x[k], W1[h * K + k], v);
        y[h] = leaky(v);
    }
    float ps[4]  = {0.f, 0.f, 0.f, 0.f};
    float pss[4] = {0.f, 0.f, 0.f, 0.f};
#pragma unroll
    for (int h = 0; h < HDIM; ++h) {
        float v = b2[h];
#pragma unroll
        for (int k = 0; k < HDIM; ++k) v = fmaf(y[k], W2[h * HDIM + k], v);
        v = leaky(v);
        out[i * HDIM + h] = v;
        const int g = h >> 3;                 /* compile-time after unroll */
        ps[g] += v; pss[g] = fmaf(v, v, pss[g]);
    }
#pragma unroll
    for (int off = 32; off; off >>= 1) {
#pragma unroll
        for (int g = 0; g < 4; ++g) {
            ps[g]  += __shfl_down(ps[g],  off, 64);
            pss[g] += __shfl_down(pss[g], off, 64);
        }
    }
    if (t == 0) {
#pragma unroll
        for (int g = 0; g < 4; ++g) {
            partials[g * 32 + blockIdx.x]       = ps[g];
            partials[128 + g * 32 + blockIdx.x] = pss[g];
        }
    }
}

/* ------- GroupNorm apply (final output): reduces block-partials inline ------- */
__global__ __launch_bounds__(256) void gn_apply_kernel(
    const float* __restrict__ x, const float* __restrict__ partials,
    const float* __restrict__ gw, const float* __restrict__ gb,
    float* __restrict__ out)
{
    const int idx = blockIdx.x * 256 + threadIdx.x;   /* < NPTS*HDIM */
    const int c = idx & (HDIM - 1);
    const int g = c >> 3;
    float s = 0.f, q = 0.f;
#pragma unroll
    for (int b = 0; b < 32; ++b) {
        s += partials[g * 32 + b];
        q += partials[128 + g * 32 + b];
    }
    const float inv = 1.f / (8.f * NPTS);
    const float mu = s * inv;
    const float rs = rsqrtf(q * inv - mu * mu + EPSV);
    out[idx] = fmaf((x[idx] - mu) * rs, gw[c], gb[c]);
}

/* =================== N^2 pairwise via MFMA, scalar-pipe i-side ===============
 * grid (8, 128): x -> 256-j group (8 waves x 32 j), y -> 16-i chunk.
 * Wave owns a 32-j tile; i-loop FULLY UNROLLED (16 iterations, all indices
 * static) with per-i VGPR accumulators and NO LDS ops inside the loop:
 *   - i-side pack via wave-uniform s_load batches (scalar pipe)
 *   - no ds_atomic in the loop -> lgkmcnt tracks only s_loads -> the
 *     scheduler can software-pipeline loads across iterations
 *   - sched_barrier(0) every 8 iterations bounds register live-ranges
 *     (round-5 lesson; keeps the MFMA d-results from all batching up)
 * Per (i, j-tile): one v_mfma_f32_32x32x16_bf16:
 *   D[j][h] = U[j][k] * A2e[k][h]; k=0..7 = w*relu(cut_c) (window folded,
 *   w>0), k=8 = w against B2[h] (bias slot), k>8 = 0.
 * A-frag row=lane&31, k=8*(lane>>5)+e; D col=lane&31,
 * row=(reg&3)+8*(reg>>2)+4*(lane>>5)  [verified round 6 vs reference].
 * launch_bounds(512,1): VGPR cap 256 (spill lessons rounds 2-4). */
__global__ __launch_bounds__(512, 1) void pairwise_kernel(
    const float* __restrict__ points, const float* __restrict__ nuv,
    const float* __restrict__ A2, const float* __restrict__ B2,
    const float* __restrict__ ipack,
    const float* __restrict__ traw, const float* __restrict__ partials,
    const float* __restrict__ gw, const float* __restrict__ gb,
    float* __restrict__ fout)
{
    const int t     = threadIdx.x;
    const int lane  = t & 63;
    const int h     = lane & 31;          /* B/D column; local j for A-frag */
    const int khalf = lane >> 5;
    const int ibase = blockIdx.y * ICH;
    const int jt0   = blockIdx.x * 256 + (t >> 6) * 32;

    __shared__ float sacc[ICH][32];       /* 2 KB tile accumulator */
    if (t < ICH * 32) ((float*)sacc)[t] = 0.f;
    __syncthreads();

    /* ---- per-lane j-side (loaded once) ---- */
    const int j = jt0 + h;
    const float pjx = points[j * 3 + 0] * PSCALE;
    const float pjy = points[j * 3 + 1] * PSCALE;
    const float pjz = points[j * 3 + 2] * PSCALE;
    const float njx = nuv[j * 9 + 0], njy = nuv[j * 9 + 1], njz = nuv[j * 9 + 2];

    /* ---- constant B fragment: A2e[k][h] ---- */
    bf16x8 bfrag;
#pragma unroll
    for (int e = 0; e < 8; ++e) {
        const float bv = (khalf == 0) ? A2[h * 8 + e] : (e == 0 ? B2[h] : 0.f);
        bfrag[e] = (__bf16)bv;
    }

    /* ---- GroupNorm-on-the-fly f registers (16 per lane) ---- */
    const int g4 = h >> 3;
    float s = 0.f, q = 0.f;
#pragma unroll
    for (int b = 0; b < 32; ++b) {
        s += partials[g4 * 32 + b];
        q += partials[128 + g4 * 32 + b];
    }
    const float inv = 1.f / (8.f * NPTS);
    const float mu = s * inv;
    const float rs = rsqrtf(q * inv - mu * mu + EPSV);
    const float alpha = rs * gw[h];
    const float gamma = fmaf(-mu, alpha, gb[h]);
    float freg[16];
#pragma unroll
    for (int r = 0; r < 16; ++r) {
        const int jr = (r & 3) + 8 * (r >> 2) + 4 * khalf;  /* D row for reg r */
        freg[r] = fmaf(traw[(jt0 + jr) * HDIM + h], alpha, gamma);
    }

    f32x16 czero;
#pragma unroll
    for (int e = 0; e < 16; ++e) czero[e] = 0.f;

    /* ---- fully-unrolled i-loop, VGPR accumulators ---- */
    float accv[ICH];
#pragma unroll
    for (int il = 0; il < ICH; ++il) accv[il] = 0.f;

#pragma unroll
    for (int il = 0; il < ICH; ++il) {
        const float4* ip4 = (const float4*)(ipack + (ibase + il) * IPK);
        const float4 m0 = ip4[0], m1 = ip4[1], m2 = ip4[2], m3 = ip4[3];
        const float4 m4 = ip4[4], m5 = ip4[5], m6 = ip4[6], m7 = ip4[7];
        const float4 G0 = ip4[8], G1 = ip4[9];

        const float dx = pjx - G0.x, dy = pjy - G0.y, dz = pjz - G0.z;
        const float sq = fmaf(dx, dx, fmaf(dy, dy, dz * dz));
        const float dt = fmaf(G0.w, njx, fmaf(G1.x, njy, G1.y * njz));
        const float tt = 2.f - dt;
        const float wv = __expf(-sq * tt * tt);

        float u[8];
        u[0] = wv * fmaxf(fmaf(m0.x, dx, fmaf(m0.y, dy, fmaf(m0.z, dz, m0.w))), 0.f);
        u[1] = wv * fmaxf(fmaf(m1.x, dx, fmaf(m1.y, dy, fmaf(m1.z, dz, m1.w))), 0.f);
        u[2] = wv * fmaxf(fmaf(m2.x, dx, fmaf(m2.y, dy, fmaf(m2.z, dz, m2.w))), 0.f);
        u[3] = wv * fmaxf(fmaf(m3.x, dx, fmaf(m3.y, dy, fmaf(m3.z, dz, m3.w))), 0.f);
        u[4] = wv * fmaxf(fmaf(m4.x, dx, fmaf(m4.y, dy, fmaf(m4.z, dz, m4.w))), 0.f);
        u[5] = wv * fmaxf(fmaf(m5.x, dx, fmaf(m5.y, dy, fmaf(m5.z, dz, m5.w))), 0.f);
        u[6] = wv * fmaxf(fmaf(m6.x, dx, fmaf(m6.y, dy, fmaf(m6.z, dz, m6.w))), 0.f);
        u[7] = wv * fmaxf(fmaf(m7.x, dx, fmaf(m7.y, dy, fmaf(m7.z, dz, m7.w))), 0.f);

        bf16x8 afrag;
        afrag[0] = (__bf16)(khalf == 0 ? u[0] : wv);
#pragma unroll
        for (int e = 1; e < 8; ++e)
            afrag[e] = (__bf16)(khalf == 0 ? u[e] : 0.f);

        const f32x16 d = __builtin_amdgcn_mfma_f32_32x32x16_bf16(
            afrag, bfrag, czero, 0, 0, 0);

        float p0 = 0.f, p1 = 0.f, p2 = 0.f, p3 = 0.f;
#pragma unroll
        for (int r = 0; r < 16; r += 4) {
            p0 = fmaf(fmaxf(d[r],     0.f), freg[r],     p0);
            p1 = fmaf(fmaxf(d[r + 1], 0.f), freg[r + 1], p1);
            p2 = fmaf(fmaxf(d[r + 2], 0.f), freg[r + 2], p2);
            p3 = fmaf(fmaxf(d[r + 3], 0.f), freg[r + 3], p3);
        }
        accv[il] = (p0 + p1) + (p2 + p3);

        if ((il & 7) == 7) __builtin_amdgcn_sched_barrier(0);
    }

    /* ---- block-level reduction via LDS atomics (outside the hot loop) ---- */
#pragma unroll
    for (int il = 0; il < ICH; ++il)
        atomicAdd(&sacc[il][h], accv[il]);
    __syncthreads();

    /* ---- flush tile to global (512 threads = 512 cells) ---- */
    {
        const int il0 = t >> 5, h0 = t & 31;
        atomicAdd(&fout[(ibase + il0) * HDIM + h0], sacc[il0][h0]);
    }
}

extern "C" void kernel_launch(void* const* d_in, const int* in_sizes, int n_in,
                              void* d_out, int out_size, void* d_ws, size_t ws_size,
                              hipStream_t stream)
{
    const float* points   = (const float*)d_in[0];
    const float* nuv      = (const float*)d_in[1];
    const float* features = (const float*)d_in[2];
    const float* W_in1    = (const float*)d_in[3];
    const float* b_in1    = (const float*)d_in[4];
    const float* W_in2    = (const float*)d_in[5];
    const float* b_in2    = (const float*)d_in[6];
    const float* g_in_w   = (const float*)d_in[7];
    const float* g_in_b   = (const float*)d_in[8];
    const float* A1       = (const float*)d_in[9];
    const float* A2       = (const float*)d_in[10];
    const float* W_out1   = (const float*)d_in[11];
    const float* b_out1   = (const float*)d_in[12];
    const float* W_out2   = (const float*)d_in[13];
    const float* b_out2   = (const float*)d_in[14];
    const float* g_out_w  = (const float*)d_in[15];
    const float* g_out_b  = (const float*)d_in[16];
    const float* B1       = (const float*)d_in[17];
    const float* B2       = (const float*)d_in[18];

    float* ws    = (float*)d_ws;
    float* t2a   = ws;               /* N*H raw net_in output */
    float* t2b   = ws + 65536;       /* N*H raw net_out output */
    float* fout  = ws + 131072;      /* N*H pairwise accumulator */
    float* ipack = ws + 196608;      /* N*IPK = 98304 */
    float* part1 = ws + 294912;      /* 256 floats */
    float* part2 = ws + 295168;      /* 256 floats */
    float* out   = (float*)d_out;

    /* net_in (+stats partials, +zero fout, +ipack) */
    net2_kernel<IDIM><<<dim3(NPTS / 64), dim3(64), 0, stream>>>(
        features, W_in1, b_in1, W_in2, b_in2, t2a, part1, fout,
        points, nuv, A1, B1, ipack);

    /* all-pairs interaction (GroupNorm of f applied on the fly) */
    pairwise_kernel<<<dim3(NPTS / 256, NPTS / ICH), dim3(512), 0, stream>>>(
        points, nuv, A2, B2, ipack, t2a, part1, g_in_w, g_in_b, fout);

    /* net_out (+stats partials), then final normalize -> out */
    net2_kernel<HDIM><<<dim3(NPTS / 64), dim3(64), 0, stream>>>(
        fout, W_out1, b_out1, W_out2, b_out2, t2b, part2, nullptr,
        nullptr, nullptr, nullptr, nullptr, nullptr);
    gn_apply_kernel<<<dim3(NPTS * HDIM / 256), dim3(256), 0, stream>>>(
        t2b, part2, g_out_w, g_out_b, out);
}

// Round 9
// 165.351 us; speedup vs baseline: 1.6114x; 1.6114x over previous
//
#include <hip/hip_runtime.h>
#include <hip/hip_bf16.h>

#define NPTS   2048
#define IDIM   16
#define HDIM   32
#define CUTSN  8
#define EPSV   1e-5f
#define PSCALE 0.07856742013183862f   /* 1/(sqrt(2)*9) */
#define ICH    16                     /* i-rows per block chunk */
#define IPK    48                     /* floats per ipack row (192B aligned) */

typedef __bf16 bf16x8 __attribute__((ext_vector_type(8)));
typedef float  f32x16 __attribute__((ext_vector_type(16)));

__device__ __forceinline__ float leaky(float x) { return x >= 0.f ? x : 0.2f * x; }

/* ------- two-layer MLP (per-row) + GroupNorm partial sums (+ipack/zero) -------
 * 32 blocks x 64 threads (one wave), one row per thread. partials (256 floats):
 * [g*32 + block] = group sums, [128 + g*32 + block] = group sumsq.
 * ipack row (40 used of 48):
 *   c=0..7 : {Mx,My,Mz,bias'}  M_c = A1_c @ nuv_i, bias' = B1_c - M_c.(s p_i)
 *   [32..35]: {-2 s p_i, q_i}   q_i = |s p_i|^2
 *   [36..39]: {n_i, 0}                                              */
template <int K>
__global__ __launch_bounds__(64) void net2_kernel(
    const float* __restrict__ xin,
    const float* __restrict__ W1, const float* __restrict__ b1,
    const float* __restrict__ W2, const float* __restrict__ b2,
    float* __restrict__ out, float* __restrict__ partials,
    float* __restrict__ zbuf,
    const float* __restrict__ points, const float* __restrict__ nuv,
    const float* __restrict__ A1, const float* __restrict__ B1,
    float* __restrict__ ipack)
{
    const int t = threadIdx.x;
    const int i = blockIdx.x * 64 + t;
    if (zbuf) {
#pragma unroll
        for (int e = 0; e < 8; ++e)
            *(float4*)&zbuf[i * HDIM + e * 4] = make_float4(0.f, 0.f, 0.f, 0.f);
    }
    if (ipack) {
        float* ip = ipack + i * IPK;
        const float spx = points[i * 3 + 0] * PSCALE;
        const float spy = points[i * 3 + 1] * PSCALE;
        const float spz = points[i * 3 + 2] * PSCALE;
#pragma unroll
        for (int c = 0; c < 8; ++c) {
            float m0 = 0.f, m1 = 0.f, m2 = 0.f;
#pragma unroll
            for (int a = 0; a < 3; ++a) {
                const float wA = A1[c * 3 + a];
                m0 = fmaf(wA, nuv[i * 9 + a * 3 + 0], m0);
                m1 = fmaf(wA, nuv[i * 9 + a * 3 + 1], m1);
                m2 = fmaf(wA, nuv[i * 9 + a * 3 + 2], m2);
            }
            const float bp = B1[c] - (m0 * spx + m1 * spy + m2 * spz);
            *(float4*)&ip[c * 4] = make_float4(m0, m1, m2, bp);
        }
        *(float4*)&ip[32] = make_float4(-2.f * spx, -2.f * spy, -2.f * spz,
                                        spx * spx + spy * spy + spz * spz);
        *(float4*)&ip[36] = make_float4(nuv[i * 9 + 0], nuv[i * 9 + 1],
                                        nuv[i * 9 + 2], 0.f);
        *(float4*)&ip[40] = make_float4(0.f, 0.f, 0.f, 0.f);
        *(float4*)&ip[44] = make_float4(0.f, 0.f, 0.f, 0.f);
    }

    float x[K];
#pragma unroll
    for (int k = 0; k < K; ++k) x[k] = xin[i * K + k];

    float y[HDIM];
#pragma unroll
    for (int h = 0; h < HDIM; ++h) {
        float v = b1[h];
#pragma unroll
        for (int k = 0; k < K; ++k) v = fmaf(x[k], W1[h * K + k], v);
        y[h] = leaky(v);
    }
    float ps[4]  = {0.f, 0.f, 0.f, 0.f};
    float pss[4] = {0.f, 0.f, 0.f, 0.f};
#pragma unroll
    for (int h = 0; h < HDIM; ++h) {
        float v = b2[h];
#pragma unroll
        for (int k = 0; k < HDIM; ++k) v = fmaf(y[k], W2[h * HDIM + k], v);
        v = leaky(v);
        out[i * HDIM + h] = v;
        const int g = h >> 3;                 /* compile-time after unroll */
        ps[g] += v; pss[g] = fmaf(v, v, pss[g]);
    }
#pragma unroll
    for (int off = 32; off; off >>= 1) {
#pragma unroll
        for (int g = 0; g < 4; ++g) {
            ps[g]  += __shfl_down(ps[g],  off, 64);
            pss[g] += __shfl_down(pss[g], off, 64);
        }
    }
    if (t == 0) {
#pragma unroll
        for (int g = 0; g < 4; ++g) {
            partials[g * 32 + blockIdx.x]       = ps[g];
            partials[128 + g * 32 + blockIdx.x] = pss[g];
        }
    }
}

/* ------- GroupNorm apply (final output): reduces block-partials inline ------- */
__global__ __launch_bounds__(256) void gn_apply_kernel(
    const float* __restrict__ x, const float* __restrict__ partials,
    const float* __restrict__ gw, const float* __restrict__ gb,
    float* __restrict__ out)
{
    const int idx = blockIdx.x * 256 + threadIdx.x;   /* < NPTS*HDIM */
    const int c = idx & (HDIM - 1);
    const int g = c >> 3;
    float s = 0.f, q = 0.f;
#pragma unroll
    for (int b = 0; b < 32; ++b) {
        s += partials[g * 32 + b];
        q += partials[128 + g * 32 + b];
    }
    const float inv = 1.f / (8.f * NPTS);
    const float mu = s * inv;
    const float rs = rsqrtf(q * inv - mu * mu + EPSV);
    out[idx] = fmaf((x[idx] - mu) * rs, gw[c], gb[c]);
}

/* =================== N^2 pairwise via MFMA, two j-tiles per wave ============
 * grid (4, 128): x -> 512-j group (8 waves x 64 j), y -> 16-i chunk.
 * Each wave owns TWO 32-j tiles (A,B) and loops the chunk's 16 i's,
 * 2-deep pipelined on the i-pack s_loads (r7-proven skeleton; r8 showed a
 * full unroll exceeds the SGPR file -> vector loads -> spill. Keep 2-deep).
 * The two tiles are fully independent chains sharing one i-pack: two MFMA
 * d-results in flight -> forces >=64 VGPR and gives ILP at every stall.
 * Per (i, tile): one v_mfma_f32_32x32x16_bf16, K-pack k=0..7 = w*relu(cut),
 * k=8 = w vs B2[h] bias slot. A-frag row=lane&31, k=8*(lane>>5)+e; D
 * col=lane&31, row=(reg&3)+8*(reg>>2)+4*(lane>>5)  [verified round 6].
 * sched_barrier(0) per iteration bounds live-range batching (r5/r8 lesson).
 * All register arrays static-indexed (rule #20). launch_bounds(512,1). */
__global__ __launch_bounds__(512, 1) void pairwise_kernel(
    const float* __restrict__ points, const float* __restrict__ nuv,
    const float* __restrict__ A2, const float* __restrict__ B2,
    const float* __restrict__ ipack,
    const float* __restrict__ traw, const float* __restrict__ partials,
    const float* __restrict__ gw, const float* __restrict__ gb,
    float* __restrict__ fout)
{
    const int t     = threadIdx.x;
    const int lane  = t & 63;
    const int h     = lane & 31;          /* B/D column; local j within tile */
    const int khalf = lane >> 5;
    const int ibase = blockIdx.y * ICH;
    const int jt0   = blockIdx.x * 512 + (t >> 6) * 64;   /* tile A base */

    __shared__ float sacc[ICH][32];       /* 2 KB tile accumulator */
    if (t < ICH * 32) ((float*)sacc)[t] = 0.f;
    __syncthreads();

    /* ---- per-lane j-side for both tiles (loaded once) ---- */
    const int jA = jt0 + h, jB = jt0 + 32 + h;
    const float pjxA = points[jA * 3 + 0] * PSCALE;
    const float pjyA = points[jA * 3 + 1] * PSCALE;
    const float pjzA = points[jA * 3 + 2] * PSCALE;
    const float njxA = nuv[jA * 9 + 0], njyA = nuv[jA * 9 + 1], njzA = nuv[jA * 9 + 2];
    const float qjA  = fmaf(pjxA, pjxA, fmaf(pjyA, pjyA, pjzA * pjzA));
    const float pjxB = points[jB * 3 + 0] * PSCALE;
    const float pjyB = points[jB * 3 + 1] * PSCALE;
    const float pjzB = points[jB * 3 + 2] * PSCALE;
    const float njxB = nuv[jB * 9 + 0], njyB = nuv[jB * 9 + 1], njzB = nuv[jB * 9 + 2];
    const float qjB  = fmaf(pjxB, pjxB, fmaf(pjyB, pjyB, pjzB * pjzB));

    /* ---- constant B fragment: A2e[k][h] (same for both tiles) ---- */
    bf16x8 bfrag;
#pragma unroll
    for (int e = 0; e < 8; ++e) {
        const float bv = (khalf == 0) ? A2[h * 8 + e] : (e == 0 ? B2[h] : 0.f);
        bfrag[e] = (__bf16)bv;
    }

    /* ---- GroupNorm-on-the-fly f registers, 16 per tile ---- */
    const int g4 = h >> 3;
    float s = 0.f, q = 0.f;
#pragma unroll
    for (int b = 0; b < 32; ++b) {
        s += partials[g4 * 32 + b];
        q += partials[128 + g4 * 32 + b];
    }
    const float inv = 1.f / (8.f * NPTS);
    const float mu = s * inv;
    const float rs = rsqrtf(q * inv - mu * mu + EPSV);
    const float alpha = rs * gw[h];
    const float gamma = fmaf(-mu, alpha, gb[h]);
    float fregA[16], fregB[16];
#pragma unroll
    for (int r = 0; r < 16; ++r) {
        const int jr = (r & 3) + 8 * (r >> 2) + 4 * khalf;  /* D row for reg r */
        fregA[r] = fmaf(traw[(jt0 + jr) * HDIM + h],      alpha, gamma);
        fregB[r] = fmaf(traw[(jt0 + 32 + jr) * HDIM + h], alpha, gamma);
    }

    f32x16 czero;
#pragma unroll
    for (int e = 0; e < 16; ++e) czero[e] = 0.f;

    float accv[ICH];
#pragma unroll
    for (int il = 0; il < ICH; ++il) accv[il] = 0.f;

/* load one i's pack into named register buffers (wave-uniform -> s_load) */
#define LOADI(M, G8, G9, il) do {                                             \
        const float4* ip4 = (const float4*)(ipack + (ibase + (il)) * IPK);    \
        M[0] = ip4[0]; M[1] = ip4[1]; M[2] = ip4[2]; M[3] = ip4[3];           \
        M[4] = ip4[4]; M[5] = ip4[5]; M[6] = ip4[6]; M[7] = ip4[7];           \
        G8 = ip4[8]; G9 = ip4[9];                                             \
    } while (0)

/* one i against BOTH 32-j tiles: two independent geometry/u/MFMA/post chains */
#define BODY2(M, G8, G9, il) do {                                             \
        const float sqA = fmaf(G8.x, pjxA, fmaf(G8.y, pjyA,                   \
                          fmaf(G8.z, pjzA, G8.w))) + qjA;                     \
        const float sqB = fmaf(G8.x, pjxB, fmaf(G8.y, pjyB,                   \
                          fmaf(G8.z, pjzB, G8.w))) + qjB;                     \
        const float dtA = fmaf(G9.x, njxA, fmaf(G9.y, njyA, G9.z * njzA));    \
        const float dtB = fmaf(G9.x, njxB, fmaf(G9.y, njyB, G9.z * njzB));    \
        const float ttA = 2.f - dtA, ttB = 2.f - dtB;                         \
        const float wvA = __expf(-sqA * ttA * ttA);                           \
        const float wvB = __expf(-sqB * ttB * ttB);                           \
        float uA[8], uB[8];                                                   \
        _Pragma("unroll")                                                     \
        for (int c = 0; c < 8; ++c) {                                         \
            uA[c] = wvA * fmaxf(fmaf(M[c].x, pjxA, fmaf(M[c].y, pjyA,         \
                                fmaf(M[c].z, pjzA, M[c].w))), 0.f);           \
            uB[c] = wvB * fmaxf(fmaf(M[c].x, pjxB, fmaf(M[c].y, pjyB,         \
                                fmaf(M[c].z, pjzB, M[c].w))), 0.f);           \
        }                                                                     \
        bf16x8 afA, afB;                                                      \
        afA[0] = (__bf16)(khalf == 0 ? uA[0] : wvA);                          \
        afB[0] = (__bf16)(khalf == 0 ? uB[0] : wvB);                          \
        _Pragma("unroll")                                                     \
        for (int e = 1; e < 8; ++e) {                                         \
            afA[e] = (__bf16)(khalf == 0 ? uA[e] : 0.f);                      \
            afB[e] = (__bf16)(khalf == 0 ? uB[e] : 0.f);                      \
        }                                                                     \
        const f32x16 dA = __builtin_amdgcn_mfma_f32_32x32x16_bf16(            \
            afA, bfrag, czero, 0, 0, 0);                                      \
        const f32x16 dB = __builtin_amdgcn_mfma_f32_32x32x16_bf16(            \
            afB, bfrag, czero, 0, 0, 0);                                      \
        float a0 = 0.f, a1 = 0.f, b0 = 0.f, b1 = 0.f;                         \
        _Pragma("unroll")                                                     \
        for (int r = 0; r < 16; r += 2) {                                     \
            a0 = fmaf(fmaxf(dA[r],     0.f), fregA[r],     a0);               \
            a1 = fmaf(fmaxf(dA[r + 1], 0.f), fregA[r + 1], a1);               \
            b0 = fmaf(fmaxf(dB[r],     0.f), fregB[r],     b0);               \
            b1 = fmaf(fmaxf(dB[r + 1], 0.f), fregB[r + 1], b1);               \
        }                                                                     \
        accv[il] = (a0 + a1) + (b0 + b1);                                     \
    } while (0)

    /* ---- 2-deep pipelined i-loop (unroll 1 keeps the SGPR window small) ---- */
    float4 MA[8], MB[8], GA8, GA9, GB8, GB9;
    LOADI(MA, GA8, GA9, 0);
#pragma unroll 1
    for (int ii = 0; ii < ICH; ii += 2) {
        LOADI(MB, GB8, GB9, ii + 1);
        BODY2(MA, GA8, GA9, ii);
        __builtin_amdgcn_sched_barrier(0);
        if (ii + 2 < ICH) LOADI(MA, GA8, GA9, ii + 2);
        BODY2(MB, GB8, GB9, ii + 1);
        __builtin_amdgcn_sched_barrier(0);
    }
#undef LOADI
#undef BODY2

    /* ---- block-level reduction via LDS atomics (outside the hot loop) ---- */
#pragma unroll
    for (int il = 0; il < ICH; ++il)
        atomicAdd(&sacc[il][h], accv[il]);
    __syncthreads();

    /* ---- flush tile to global (512 threads = 512 cells) ---- */
    {
        const int il0 = t >> 5, h0 = t & 31;
        atomicAdd(&fout[(ibase + il0) * HDIM + h0], sacc[il0][h0]);
    }
}

extern "C" void kernel_launch(void* const* d_in, const int* in_sizes, int n_in,
                              void* d_out, int out_size, void* d_ws, size_t ws_size,
                              hipStream_t stream)
{
    const float* points   = (const float*)d_in[0];
    const float* nuv      = (const float*)d_in[1];
    const float* features = (const float*)d_in[2];
    const float* W_in1    = (const float*)d_in[3];
    const float* b_in1    = (const float*)d_in[4];
    const float* W_in2    = (const float*)d_in[5];
    const float* b_in2    = (const float*)d_in[6];
    const float* g_in_w   = (const float*)d_in[7];
    const float* g_in_b   = (const float*)d_in[8];
    const float* A1       = (const float*)d_in[9];
    const float* A2       = (const float*)d_in[10];
    const float* W_out1   = (const float*)d_in[11];
    const float* b_out1   = (const float*)d_in[12];
    const float* W_out2   = (const float*)d_in[13];
    const float* b_out2   = (const float*)d_in[14];
    const float* g_out_w  = (const float*)d_in[15];
    const float* g_out_b  = (const float*)d_in[16];
    const float* B1       = (const float*)d_in[17];
    const float* B2       = (const float*)d_in[18];

    float* ws    = (float*)d_ws;
    float* t2a   = ws;               /* N*H raw net_in output */
    float* t2b   = ws + 65536;       /* N*H raw net_out output */
    float* fout  = ws + 131072;      /* N*H pairwise accumulator */
    float* ipack = ws + 196608;      /* N*IPK = 98304 */
    float* part1 = ws + 294912;      /* 256 floats */
    float* part2 = ws + 295168;      /* 256 floats */
    float* out   = (float*)d_out;

    /* net_in (+stats partials, +zero fout, +ipack) */
    net2_kernel<IDIM><<<dim3(NPTS / 64), dim3(64), 0, stream>>>(
        features, W_in1, b_in1, W_in2, b_in2, t2a, part1, fout,
        points, nuv, A1, B1, ipack);

    /* all-pairs interaction (GroupNorm of f applied on the fly) */
    pairwise_kernel<<<dim3(NPTS / 512, NPTS / ICH), dim3(512), 0, stream>>>(
        points, nuv, A2, B2, ipack, t2a, part1, g_in_w, g_in_b, fout);

    /* net_out (+stats partials), then final normalize -> out */
    net2_kernel<HDIM><<<dim3(NPTS / 64), dim3(64), 0, stream>>>(
        fout, W_out1, b_out1, W_out2, b_out2, t2b, part2, nullptr,
        nullptr, nullptr, nullptr, nullptr, nullptr);
    gn_apply_kernel<<<dim3(NPTS * HDIM / 256), dim3(256), 0, stream>>>(
        t2b, part2, g_out_w, g_out_b, out);
}